// Round 18
// baseline (72.098 us; speedup 1.0000x reference)
//
#include <hip/hip_runtime.h>
#include <hip/hip_bf16.h>

typedef __attribute__((ext_vector_type(8))) short bf16x8;
typedef __attribute__((ext_vector_type(4))) float f32x4;

__device__ __forceinline__ ushort f2bf(float x) {
  unsigned u = __float_as_uint(x);
  u = (u + 0x7FFFu + ((u >> 16) & 1u)) >> 16;
  return (ushort)u;
}

// Pack K (f32 [256][1024]) into MFMA-fragment order:
// chunk c = (otile 0..63, ks 0..7, lane 0..63); chunk holds 8 bf16:
//   o = otile*16 + (lane&15), k = ks*32 + (lane>>4)*8 + e
__global__ void WV_kconv(const float* __restrict__ K, ushort* __restrict__ KtP) {
  int c = blockIdx.x * 256 + threadIdx.x;  // 0..32767
  int otile = c >> 9, ks = (c >> 6) & 7, lane = c & 63;
  int o = otile * 16 + (lane & 15);
  int kb = ks * 32 + (lane >> 4) * 8;
  bf16x8 w;
  #pragma unroll
  for (int e = 0; e < 8; ++e)
    w[e] = (short)f2bf(K[(size_t)(kb + e) * 1024 + o]);
  *reinterpret_cast<bf16x8*>(KtP + (size_t)c * 8) = w;
}

// Block (b,h): h = i-QUARTER (64 rows) -> 32 KB LDS. 8 waves; wave owns
// an o-strip of 128 (2 og x 4 ot x 16).
// R18 vs R17: full 2-deep pipeline — Af (LDS) fragments for ks+1 are
// ds_read BEFORE the ks MFMA block, so the lgkm wait lands on data issued
// ~200 cyc earlier (R17 post-mortem: exposed fresh-ds_read latency was
// the remaining stall). Regs ~150 -> launch_bounds (512,1) to avoid the
// 128-cap spill; 3 waves/SIMD. T5 setprio around the MFMA cluster.
__global__ __launch_bounds__(512, 1) void WV_main(
    const float* __restrict__ A, const ushort* __restrict__ KtP,
    float* __restrict__ out) {
  __shared__ short As[64 * 256];  // 32 KB
  const int bh = blockIdx.x;
  const int b = bh >> 2, h = bh & 3;
  const float* Ah = A + (size_t)b * 65536 + (size_t)h * 16384;
  const int t = threadIdx.x;

  // ---- stage 64 rows: fp32 -> bf16, swizzle byte ^= (row&7)<<4 ----
  #pragma unroll
  for (int it = 0; it < 4; ++it) {
    int c = it * 512 + t;  // chunk of 8 floats
    int m = c >> 5;        // local row 0..63
    int s = c & 31;        // 16B slot within row
    const float4* p = reinterpret_cast<const float4*>(Ah) + c * 2;
    float4 v0 = p[0], v1 = p[1];
    bf16x8 w;
    w[0] = (short)f2bf(v0.x); w[1] = (short)f2bf(v0.y);
    w[2] = (short)f2bf(v0.z); w[3] = (short)f2bf(v0.w);
    w[4] = (short)f2bf(v1.x); w[5] = (short)f2bf(v1.y);
    w[6] = (short)f2bf(v1.z); w[7] = (short)f2bf(v1.w);
    int byteoff = m * 512 + ((s * 16) ^ ((m & 7) << 4));
    *reinterpret_cast<bf16x8*>(reinterpret_cast<char*>(As) + byteoff) = w;
  }
  __syncthreads();

  const int wave = t >> 6, lane = t & 63;
  const int lo = lane & 15;   // col within tile (B,D) / row (A)
  const int hi = lane >> 4;   // 0..3
  const int wob = wave * 128;

  // prologue: og=0, ks=0 B fragments
  bf16x8 Bc[4];
  #pragma unroll
  for (int ot = 0; ot < 4; ++ot)
    Bc[ot] = *reinterpret_cast<const bf16x8*>(
        KtP + ((size_t)((wave * 8 + ot) * 8 + 0) * 64 + lane) * 8);

  #pragma unroll 1
  for (int og = 0; og < 2; ++og) {
    const int otb = wave * 8 + og * 4;  // o-tile base

    f32x4 acc[4][4];
    #pragma unroll
    for (int a1 = 0; a1 < 4; ++a1)
      #pragma unroll
      for (int a2 = 0; a2 < 4; ++a2)
        acc[a1][a2] = (f32x4){0.f, 0.f, 0.f, 0.f};

    // prologue: A fragments for ks=0 (byte col = ks*64 + hi*16)
    bf16x8 Afc[4];
    #pragma unroll
    for (int itl = 0; itl < 4; ++itl) {
      int m = itl * 16 + lo;
      int byteoff = m * 512 + ((hi * 16) ^ ((m & 7) << 4));
      Afc[itl] = *reinterpret_cast<const bf16x8*>(
          reinterpret_cast<char*>(As) + byteoff);
    }

    #pragma unroll 1
    for (int ks = 0; ks < 8; ++ks) {
      bf16x8 Bn[4], Afn[4];
      const bool pfB = (ks < 7) || (og == 0);  // wave-uniform
      if (ks < 7) {  // issue next-ks A ds_reads BEFORE the MFMA block
        #pragma unroll
        for (int itl = 0; itl < 4; ++itl) {
          int m = itl * 16 + lo;
          int byteoff = m * 512 + ((((ks + 1) * 64 + hi * 16)) ^ ((m & 7) << 4));
          Afn[itl] = *reinterpret_cast<const bf16x8*>(
              reinterpret_cast<char*>(As) + byteoff);
        }
      }
      if (pfB) {  // next B fragments: same og next ks, or og=1 ks=0
        const int notb = (ks < 7) ? otb : (wave * 8 + 4);
        const int nks = (ks < 7) ? (ks + 1) : 0;
        #pragma unroll
        for (int ot = 0; ot < 4; ++ot)
          Bn[ot] = *reinterpret_cast<const bf16x8*>(
              KtP + ((size_t)((notb + ot) * 8 + nks) * 64 + lane) * 8);
      }
      __builtin_amdgcn_s_setprio(1);
      #pragma unroll
      for (int itl = 0; itl < 4; ++itl) {
        #pragma unroll
        for (int ot = 0; ot < 4; ++ot)
          acc[itl][ot] = __builtin_amdgcn_mfma_f32_16x16x32_bf16(
              Afc[itl], Bc[ot], acc[itl][ot], 0, 0, 0);
      }
      __builtin_amdgcn_s_setprio(0);
      if (ks < 7) {
        #pragma unroll
        for (int itl = 0; itl < 4; ++itl) Afc[itl] = Afn[itl];
      }
      if (pfB) {
        #pragma unroll
        for (int ot = 0; ot < 4; ++ot) Bc[ot] = Bn[ot];
      }
    }

    // epilogue: per-lane weighted accumulate over itl, then ONE
    // butterfly per ot. Weights K[i0..i0+3][o(lane)] from KtP:
    // i0 = h*64+itl*16+hi*4 = kse*32+g*8+e, kse = h*2+(itl>>1),
    // g = (itl&1)*2+(hi>>1), e = (hi&1)*4.
    float p4[4] = {0.f, 0.f, 0.f, 0.f};
    #pragma unroll
    for (int itl = 0; itl < 4; ++itl) {
      const int kse = h * 2 + (itl >> 1);
      const int g = (itl & 1) * 2 + (hi >> 1);
      const int e = (hi & 1) * 4;
      #pragma unroll
      for (int ot = 0; ot < 4; ++ot) {
        const ushort* wp = KtP +
            ((size_t)((otb + ot) * 8 + kse) * 64 + lo + g * 16) * 8 + e;
        ushort4 wv = *reinterpret_cast<const ushort4*>(wp);
        f32x4 a = acc[itl][ot];
        p4[ot] += __uint_as_float((unsigned)wv.x << 16) * a[0]
                + __uint_as_float((unsigned)wv.y << 16) * a[1]
                + __uint_as_float((unsigned)wv.z << 16) * a[2]
                + __uint_as_float((unsigned)wv.w << 16) * a[3];
      }
    }
    #pragma unroll
    for (int ot = 0; ot < 4; ++ot) {
      float s = p4[ot];
      s += __shfl_xor(s, 16);
      s += __shfl_xor(s, 32);
      if (lane < 16)
        atomicAdd(&out[(size_t)b * 1024 + wob + og * 64 + ot * 16 + lane], s);
    }
  }
}

extern "C" void kernel_launch(void* const* d_in, const int* in_sizes, int n_in,
                              void* d_out, int out_size, void* d_ws, size_t ws_size,
                              hipStream_t stream) {
  const float* A = (const float*)d_in[0];   // (256,256,256) f32
  const float* K = (const float*)d_in[1];   // (256,1024)   f32
  float* out = (float*)d_out;               // (256,1024)   f32
  ushort* KtP = (ushort*)d_ws;              // packed (64,8,64,8) bf16
  hipMemsetAsync(d_out, 0, (size_t)out_size * sizeof(float), stream);
  WV_kconv<<<128, 256, 0, stream>>>(K, KtP);
  WV_main<<<1024, 512, 0, stream>>>(A, KtP, out);
}

// Round 19
// 54.910 us; speedup vs baseline: 1.3130x; 1.3130x over previous
//
#include <hip/hip_runtime.h>
#include <hip/hip_bf16.h>

typedef __attribute__((ext_vector_type(8))) short bf16x8;
typedef __attribute__((ext_vector_type(4))) float f32x4;

__device__ __forceinline__ ushort f2bf(float x) {
  unsigned u = __float_as_uint(x);
  u = (u + 0x7FFFu + ((u >> 16) & 1u)) >> 16;
  return (ushort)u;
}

// Pack K (f32 [256][1024]) into MFMA-fragment order:
// chunk c = (otile 0..63, ks 0..7, lane 0..63); chunk holds 8 bf16:
//   o = otile*16 + (lane&15), k = ks*32 + (lane>>4)*8 + e
__global__ void WV_kconv(const float* __restrict__ K, ushort* __restrict__ KtP) {
  int c = blockIdx.x * 256 + threadIdx.x;  // 0..32767
  int otile = c >> 9, ks = (c >> 6) & 7, lane = c & 63;
  int o = otile * 16 + (lane & 15);
  int kb = ks * 32 + (lane >> 4) * 8;
  bf16x8 w;
  #pragma unroll
  for (int e = 0; e < 8; ++e)
    w[e] = (short)f2bf(K[(size_t)(kb + e) * 1024 + o]);
  *reinterpret_cast<bf16x8*>(KtP + (size_t)c * 8) = w;
}

// Block (b,h): h = i-QUARTER (64 rows) -> 32 KB LDS -> 2 blocks/CU,
// 4 waves/SIMD. 8 waves; wave owns o-strip of 128.
// R19 = exact R16 structure (best measured: 54.8 us, 128 total regs at
// the wave-capacity boundary) + T5 s_setprio around the MFMA cluster
// (zero-reg; R18 bundled it with a reg-costing A-prefetch that collapsed
// occupancy — this isolates it).
__global__ __launch_bounds__(512, 2) void WV_main(
    const float* __restrict__ A, const ushort* __restrict__ KtP,
    float* __restrict__ out) {
  __shared__ short As[64 * 256];  // 32 KB
  const int bh = blockIdx.x;
  const int b = bh >> 2, h = bh & 3;
  const float* Ah = A + (size_t)b * 65536 + (size_t)h * 16384;
  const int t = threadIdx.x;

  // ---- stage 64 rows: fp32 -> bf16, swizzle byte ^= (row&7)<<4 ----
  #pragma unroll 1
  for (int it = 0; it < 4; ++it) {
    int c = it * 512 + t;  // chunk of 8 floats
    int m = c >> 5;        // local row 0..63
    int s = c & 31;        // 16B slot within row
    const float4* p = reinterpret_cast<const float4*>(Ah) + c * 2;
    float4 v0 = p[0], v1 = p[1];
    bf16x8 w;
    w[0] = (short)f2bf(v0.x); w[1] = (short)f2bf(v0.y);
    w[2] = (short)f2bf(v0.z); w[3] = (short)f2bf(v0.w);
    w[4] = (short)f2bf(v1.x); w[5] = (short)f2bf(v1.y);
    w[6] = (short)f2bf(v1.z); w[7] = (short)f2bf(v1.w);
    int byteoff = m * 512 + ((s * 16) ^ ((m & 7) << 4));
    *reinterpret_cast<bf16x8*>(reinterpret_cast<char*>(As) + byteoff) = w;
  }
  __syncthreads();

  const int wave = t >> 6, lane = t & 63;
  const int lo = lane & 15;   // col within tile (B,D) / row (A)
  const int hi = lane >> 4;   // 0..3
  const int wob = wave * 128;

  #pragma unroll 1
  for (int og = 0; og < 2; ++og) {
    float oseg[4] = {0.f, 0.f, 0.f, 0.f};
    const int otb = wave * 8 + og * 4;  // o-tile base

    f32x4 acc[4][4];
    #pragma unroll
    for (int a1 = 0; a1 < 4; ++a1)
      #pragma unroll
      for (int a2 = 0; a2 < 4; ++a2)
        acc[a1][a2] = (f32x4){0.f, 0.f, 0.f, 0.f};

    // prologue: load ks=0 fragments
    bf16x8 Bc[4];
    #pragma unroll
    for (int ot = 0; ot < 4; ++ot)
      Bc[ot] = *reinterpret_cast<const bf16x8*>(
          KtP + ((size_t)((otb + ot) * 8 + 0) * 64 + lane) * 8);

    #pragma unroll 1
    for (int ks = 0; ks < 8; ++ks) {
      bf16x8 Bn[4];
      if (ks < 7) {  // prefetch next ks (wave-uniform branch)
        #pragma unroll
        for (int ot = 0; ot < 4; ++ot)
          Bn[ot] = *reinterpret_cast<const bf16x8*>(
              KtP + ((size_t)((otb + ot) * 8 + ks + 1) * 64 + lane) * 8);
      }
      const int kk = ks * 32 + hi * 8;
      __builtin_amdgcn_s_setprio(1);
      #pragma unroll
      for (int itl = 0; itl < 4; ++itl) {
        int m = itl * 16 + lo;
        int byteoff = m * 512 + ((kk * 2) ^ ((m & 7) << 4));
        bf16x8 Af = *reinterpret_cast<const bf16x8*>(
            reinterpret_cast<char*>(As) + byteoff);
        #pragma unroll
        for (int ot = 0; ot < 4; ++ot)
          acc[itl][ot] = __builtin_amdgcn_mfma_f32_16x16x32_bf16(
              Af, Bc[ot], acc[itl][ot], 0, 0, 0);
      }
      __builtin_amdgcn_s_setprio(0);
      if (ks < 7) {
        #pragma unroll
        for (int ot = 0; ot < 4; ++ot) Bc[ot] = Bn[ot];
      }
    }

    // epilogue: weights K[i0..i0+3][o(lane)] from KtP packed layout.
    // i0 = h*64+itl*16+hi*4 = kse*32+g*8+e with kse = h*2+(itl>>1),
    // g = (itl&1)*2+(hi>>1), e = (hi&1)*4.
    #pragma unroll
    for (int itl = 0; itl < 4; ++itl) {
      const int kse = h * 2 + (itl >> 1);
      const int g = (itl & 1) * 2 + (hi >> 1);
      const int e = (hi & 1) * 4;
      #pragma unroll
      for (int ot = 0; ot < 4; ++ot) {
        const ushort* wp = KtP +
            ((size_t)((otb + ot) * 8 + kse) * 64 + lo + g * 16) * 8 + e;
        ushort4 wv = *reinterpret_cast<const ushort4*>(wp);
        f32x4 a = acc[itl][ot];
        float s = __uint_as_float((unsigned)wv.x << 16) * a[0]
                + __uint_as_float((unsigned)wv.y << 16) * a[1]
                + __uint_as_float((unsigned)wv.z << 16) * a[2]
                + __uint_as_float((unsigned)wv.w << 16) * a[3];
        s += __shfl_xor(s, 16);
        s += __shfl_xor(s, 32);
        oseg[ot] += s;
      }
    }

    if (lane < 16) {
      #pragma unroll
      for (int ot = 0; ot < 4; ++ot)
        atomicAdd(&out[(size_t)b * 1024 + wob + og * 64 + ot * 16 + lane],
                  oseg[ot]);
    }
  }
}

extern "C" void kernel_launch(void* const* d_in, const int* in_sizes, int n_in,
                              void* d_out, int out_size, void* d_ws, size_t ws_size,
                              hipStream_t stream) {
  const float* A = (const float*)d_in[0];   // (256,256,256) f32
  const float* K = (const float*)d_in[1];   // (256,1024)   f32
  float* out = (float*)d_out;               // (256,1024)   f32
  ushort* KtP = (ushort*)d_ws;              // packed (64,8,64,8) bf16
  hipMemsetAsync(d_out, 0, (size_t)out_size * sizeof(float), stream);
  WV_kconv<<<128, 256, 0, stream>>>(K, KtP);
  WV_main<<<1024, 512, 0, stream>>>(A, KtP, out);
}